// Round 1
// baseline (3995.093 us; speedup 1.0000x reference)
//
#include <hip/hip_runtime.h>
#include <stdint.h>

// ====== variant switches for XLA:CPU transcendental reconstruction ======
// Flip these across rounds if absmax indicates trajectory divergence.
#define XLA_LOG_TAIL_A 1   // 1: t+=y; t+=e*q2 (XLA 2017 tail)  0: t+=e*q2; t+=y (new Eigen)
#define XLA_USE_FMA    0   // 0: VSL::MulAdd = Add(Mul()) (fast-math off)  1: fmuladd

#if XLA_USE_FMA
#define MADD(a,b,c) __builtin_fmaf((a),(b),(c))
#else
#define MADD(a,b,c) ((a)*(b)+(c))
#endif

#define N_NEUR 2048
#define HALF_N 1024

// ---------------- threefry2x32 (exact JAX primitive) ----------------
__device__ __forceinline__ uint32_t rotl32(uint32_t x, int r) {
  return (x << r) | (x >> (32 - r));
}

__device__ __forceinline__ void tf2x32(uint32_t k0, uint32_t k1,
                                       uint32_t& x0, uint32_t& x1) {
  const uint32_t k2 = k0 ^ k1 ^ 0x1BD11BDAu;
  x0 += k0; x1 += k1;
#define TF_R(r) { x0 += x1; x1 = rotl32(x1, r); x1 ^= x0; }
  TF_R(13) TF_R(15) TF_R(26) TF_R(6)
  x0 += k1; x1 += k2 + 1u;
  TF_R(17) TF_R(29) TF_R(16) TF_R(24)
  x0 += k2; x1 += k0 + 2u;
  TF_R(13) TF_R(15) TF_R(26) TF_R(6)
  x0 += k0; x1 += k1 + 3u;
  TF_R(17) TF_R(29) TF_R(16) TF_R(24)
  x0 += k1; x1 += k2 + 4u;
  TF_R(13) TF_R(15) TF_R(26) TF_R(6)
  x0 += k2; x1 += k0 + 5u;
#undef TF_R
}

__device__ __forceinline__ float u01_from_bits(uint32_t bits) {
#pragma clang fp contract(off)
  float f = __uint_as_float((bits >> 9) | 0x3f800000u);
  return f - 1.0f;   // *(1-0)+0 and max(0,.) are exact no-ops
}

// ---------------- XLA:CPU GenerateVF32Log (Cephes, Estrin poly) ----------------
__device__ __forceinline__ float xla_log(float xin) {
#pragma clang fp contract(off)
  float t0 = fmaxf(xin, __uint_as_float(0x00800000u));  // cut off denormals
  uint32_t bits = __float_as_uint(t0);
  int em = (int)(bits >> 23) - 127;
  t0 = __uint_as_float((bits & 0x807fffffu) | 0x3f000000u);  // mantissa in [0.5,1)
  float e = 1.0f + (float)em;
  const bool mlt = t0 < (float)0.707106781186547524;
  float tmp1 = mlt ? t0 : 0.0f;
  t0 = t0 - 1.0f;
  e = e - (mlt ? 1.0f : 0.0f);
  t0 = t0 + tmp1;
  float x2 = t0 * t0;
  float x3 = x2 * t0;
  float y  = MADD(t0, (float)7.0376836292E-2, (float)-1.1514610310E-1);
  float ya = MADD(t0, (float)-1.2420140846E-1, (float)1.4249322787E-1);
  float yb = MADD(t0, (float)2.0000714765E-1, (float)-2.4999993993E-1);
  y  = MADD(y,  t0, (float)1.1676998740E-1);
  ya = MADD(ya, t0, (float)-1.6668057665E-1);
  yb = MADD(yb, t0, (float)3.3333331174E-1);
  y  = MADD(y, x3, ya);
  y  = MADD(y, x3, yb);
  y  = y * x3;
  float ey1 = e * (float)-2.12194440e-4;
  float hx2 = x2 * 0.5f;
  y = y + ey1;
  t0 = t0 - hx2;
  float ey2 = e * (float)0.693359375;
#if XLA_LOG_TAIL_A
  t0 = t0 + y;
  t0 = t0 + ey2;
#else
  t0 = t0 + ey2;
  t0 = t0 + y;
#endif
  if (xin == 0.0f) return -__builtin_inff();
  return t0;
}

// ---------------- XLA:CPU GenerateVF32Exp (old Cephes structure) ----------------
__device__ __forceinline__ float xla_exp(float xin) {
#pragma clang fp contract(off)
  float x = fmaxf(xin, (float)-88.3762626647949);
  x = fminf(x, (float)88.3762626647950);
  float fx = floorf(MADD(x, (float)1.44269504088896341, 0.5f));
  float tmp = (float)0.693359375 * fx;
  float z = (float)-2.12194440e-4 * fx;
  x = x - tmp;
  x = x - z;
  z = x * x;
  float y = MADD(x, (float)1.9875691500E-4, (float)1.3981999507E-3);
  y = MADD(y, x, (float)8.3334519073E-3);
  y = MADD(y, x, (float)4.1665795894E-2);
  y = MADD(y, x, (float)1.6666665459E-1);
  y = MADD(y, x, (float)5.0000001201E-1);
  y = MADD(y, z, x);
  y = 1.0f + y;
  int n = (int)fx;
  float p2n = __uint_as_float((uint32_t)(n + 127) << 23);
  return fmaxf(y * p2n, xin);
}

// ---------------- XLA ElementalIrEmitter::EmitLog1p (always plain mul/add) ----
__device__ __forceinline__ float xla_log1p(float x) {
#pragma clang fp contract(off)
  float fl = xla_log(x + 1.0f);
  float fs = ((-0.5f * x) + 1.0f) * x;
  return (fabsf(x) < (float)1e-4) ? fs : fl;
}

// jax.nn.softplus(v) = logaddexp(v,0) = max(v,0) + log1p(exp(-|v|))
__device__ __forceinline__ float softplus_xla(float v) {
#pragma clang fp contract(off)
  // exact shortcut: for v>=16, exp(-v)<=1.13e-7 < ulp(v)/2 -> sum rounds to v
  if (v >= 16.0f) return v;
  float a = fabsf(v);
  float ex = xla_exp(-a);
  float lp = xla_log1p(ex);
  return fmaxf(v, 0.0f) + lp;
}

// ---------------- init: tevents/yevents = +inf, event_types = 0 ----------------
__global__ void snn_init(float* __restrict__ out, size_t inf_base,
                         size_t inf_cnt, size_t zero_cnt) {
  size_t i = (size_t)blockIdx.x * blockDim.x + threadIdx.x;
  size_t stride = (size_t)gridDim.x * blockDim.x;
  size_t total = inf_cnt + zero_cnt;
  for (size_t k = i; k < total; k += stride) {
    out[inf_base + k] = (k < inf_cnt) ? __builtin_inff() : 0.0f;
  }
}

// ---------------- precompute s_reset[step][j] = log(u)-alpha into d_ws ---------
__global__ __launch_bounds__(1024)
void snn_pre(const int* __restrict__ seedp, float* __restrict__ sres) {
#pragma clang fp contract(off)
  const int step = blockIdx.x;       // 0..T-2
  const int t = threadIdx.x;
  uint32_t seed = (uint32_t)seedp[0];
  // split(key(seed)): lane0 block (0,2), lane1 block (1,3); k_trans = second words
  uint32_t a0 = 0u, a1 = 2u; tf2x32(0u, seed, a0, a1);
  uint32_t b0 = 1u, b1 = 3u; tf2x32(0u, seed, b0, b1);
  // fold_in(k_trans, step) = cipher(k_trans, (0, step))
  uint32_t f0 = 0u, f1 = (uint32_t)step; tf2x32(a1, b1, f0, f1);
  // uniform bits: lane t holds block (t, 1024+t)
  uint32_t d0 = (uint32_t)t, d1 = (uint32_t)(t + HALF_N);
  tf2x32(f0, f1, d0, d1);
  float srA = xla_log(u01_from_bits(d0)) - 0.01f;
  float srB = xla_log(u01_from_bits(d1)) - 0.01f;
  sres[(size_t)step * N_NEUR + t] = srA;
  sres[(size_t)step * N_NEUR + HALF_N + t] = srB;
}

// ---------------- the sequential scan: 1 block, 1024 threads, 2 neurons each ---
__global__ __launch_bounds__(1024, 1)
void snn_sim(const float* __restrict__ ts, const float* __restrict__ v0,
             const float* __restrict__ i0, const float* __restrict__ ic,
             const float* __restrict__ w, const float* __restrict__ mu,
             const int* __restrict__ seedp, const float* __restrict__ sres,
             float* __restrict__ out, int T, int MS) {
#pragma clang fp contract(off)
  const int t = threadIdx.x;
  const int jA = t;
  const int jB = t + HALF_N;
  const bool use_sres = (sres != nullptr);

  float* ys   = out;                                     // [T][N][3]
  float* tev  = out + (size_t)T * N_NEUR * 3;            // [MS]
  float* yev  = tev + (size_t)MS;                        // [MS][N][3]
  float* etv  = yev + (size_t)MS * N_NEUR * 3;           // [MS][N]
  float* nspp = etv + (size_t)MS * N_NEUR;               // [1]

  // ---- keys: key = (0, seed); split -> k_init (first words), k_trans (second)
  uint32_t seed = (uint32_t)seedp[0];
  uint32_t a0 = 0u, a1 = 2u; tf2x32(0u, seed, a0, a1);
  uint32_t b0 = 1u, b1 = 3u; tf2x32(0u, seed, b0, b1);
  const uint32_t ki0 = a0, ki1 = b0;   // k_init
  const uint32_t kt0 = a1, kt1 = b1;   // k_trans

  // ---- s0 = log(uniform(k_init, (n,))) - alpha
  uint32_t c0 = (uint32_t)jA, c1 = (uint32_t)jB;
  tf2x32(ki0, ki1, c0, c1);
  float sA = xla_log(u01_from_bits(c0)) - 0.01f;
  float sB = xla_log(u01_from_bits(c1)) - 0.01f;
  float vA = v0[jA], vB = v0[jB];
  float iA = i0[jA], iB = i0[jB];
  const float icA = ic[jA], icB = ic[jB];
  const float m0 = mu[0], m1 = mu[1];

  // ---- ys[0] = y0
  {
    size_t bA = (size_t)jA * 3, bB = (size_t)jB * 3;
    ys[bA + 0] = vA; ys[bA + 1] = iA; ys[bA + 2] = sA;
    ys[bB + 0] = vB; ys[bB + 1] = iB; ys[bB + 2] = sB;
  }

  __shared__ uint32_t red[2][16];
  const int wave = t >> 6;
  const int lane = t & 63;
  int nsp = 0;

  for (int step = 0; step < T - 1; ++step) {
    const float tnxt = ts[step + 1];
    const float dt = tnxt - ts[step];

    // prefetch reset values (data-independent)
    float srpA = 0.0f, srpB = 0.0f;
    if (use_sres) {
      srpA = sres[(size_t)step * N_NEUR + jA];
      srpB = sres[(size_t)step * N_NEUR + jB];
    }

    // ---- y1 = y + dt * drift(y)
    float spA = softplus_xla(vA);
    float spB = softplus_xla(vB);
    float dvA = m0 * ((iA + icA) - vA);
    float dvB = m0 * ((iB + icB) - vB);
    float diA = (-m1) * iA;
    float diB = (-m1) * iB;
    float y1vA = vA + dt * dvA;
    float y1vB = vB + dt * dvB;
    float y1iA = iA + dt * diA;
    float y1iB = iB + dt * diB;
    float y1sA = sA + dt * spA;
    float y1sB = sB + dt * spB;
    const bool evA = (y1sA >= 0.0f);
    const bool evB = (y1sB >= 0.0f);

    // ---- first spiking neuron (argmax of bool = min index of True)
    unsigned long long mA = __ballot(evA);
    unsigned long long mB = __ballot(evB);
    uint32_t wmin = 0xFFFFFFFFu;
    if (mA) wmin = (uint32_t)(wave * 64 + __builtin_ctzll(mA));
    else if (mB) wmin = (uint32_t)(HALF_N + wave * 64 + __builtin_ctzll(mB));
    if (lane == 0) red[step & 1][wave] = wmin;
    __syncthreads();
    uint32_t e0 = red[step & 1][0];
#pragma unroll
    for (int q = 1; q < 16; ++q) {
      uint32_t r = red[step & 1][q];
      e0 = (r < e0) ? r : e0;
    }
    const bool has = (e0 != 0xFFFFFFFFu);

    float y2vA, y2iA, y2sA, y2vB, y2iB, y2sB;
    if (has) {
      uint32_t eu = __builtin_amdgcn_readfirstlane(e0);  // uniform
      float wA = w[(size_t)eu * N_NEUR + jA];
      float wB = w[(size_t)eu * N_NEUR + jB];
      float srA = y1sA, srB = y1sB;
      if (evA || evB) {
        if (use_sres) {
          if (evA) srA = srpA;
          if (evB) srB = srpB;
        } else {
          uint32_t f0 = 0u, f1 = (uint32_t)step;
          tf2x32(kt0, kt1, f0, f1);
          uint32_t d0 = (uint32_t)jA, d1 = (uint32_t)jB;
          tf2x32(f0, f1, d0, d1);
          if (evA) srA = xla_log(u01_from_bits(d0)) - 0.01f;
          if (evB) srB = xla_log(u01_from_bits(d1)) - 0.01f;
        }
      }
      y2vA = y1vA - (evA ? 1.0f : 0.0f);
      y2vB = y1vB - (evB ? 1.0f : 0.0f);
      y2iA = y1iA + wA;
      y2iB = y1iB + wB;
      y2sA = srA;
      y2sB = srB;
      if (nsp < MS) {
        if (t == 0) tev[nsp] = tnxt;
        size_t eb = (size_t)nsp * N_NEUR;
        size_t ybA = (eb + jA) * 3, ybB = (eb + jB) * 3;
        yev[ybA + 0] = y1vA; yev[ybA + 1] = y1iA; yev[ybA + 2] = y1sA;
        yev[ybB + 0] = y1vB; yev[ybB + 1] = y1iB; yev[ybB + 2] = y1sB;
        etv[eb + jA] = evA ? 1.0f : 0.0f;
        etv[eb + jB] = evB ? 1.0f : 0.0f;
      }
      nsp += 1;
    } else {
      y2vA = y1vA; y2iA = y1iA; y2sA = y1sA;
      y2vB = y1vB; y2iB = y1iB; y2sB = y1sB;
    }

    size_t rb = (size_t)(step + 1) * N_NEUR;
    size_t bA = (rb + jA) * 3, bB = (rb + jB) * 3;
    ys[bA + 0] = y2vA; ys[bA + 1] = y2iA; ys[bA + 2] = y2sA;
    ys[bB + 0] = y2vB; ys[bB + 1] = y2iB; ys[bB + 2] = y2sB;

    vA = y2vA; iA = y2iA; sA = y2sA;
    vB = y2vB; iB = y2iB; sB = y2sB;
  }

  if (t == 0) nspp[0] = (float)nsp;
}

extern "C" void kernel_launch(void* const* d_in, const int* in_sizes, int n_in,
                              void* d_out, int out_size, void* d_ws, size_t ws_size,
                              hipStream_t stream) {
  const float* ts = (const float*)d_in[0];
  const float* v0 = (const float*)d_in[1];
  const float* i0 = (const float*)d_in[2];
  const float* ic = (const float*)d_in[3];
  const float* w  = (const float*)d_in[4];
  const float* mu = (const float*)d_in[5];
  const int* seed = (const int*)d_in[6];

  const int T = in_sizes[0];      // 4000
  const int N = in_sizes[1];      // 2048 (structural assumption)
  // Recover max_spikes from output size: out = T*N*3 + MS*(1 + 3N + N) + 1
  long long rem = (long long)out_size - (long long)T * N * 3 - 1;
  int MS = (int)(rem / (1 + 4 * (long long)N));
  if (MS <= 0) MS = 512;

  // events region init (tev/yev -> +inf, et -> 0)
  size_t inf_base = (size_t)T * N * 3;
  size_t inf_cnt  = (size_t)MS + (size_t)MS * N * 3;
  size_t zero_cnt = (size_t)MS * N;
  snn_init<<<dim3(512), dim3(256), 0, stream>>>((float*)d_out, inf_base, inf_cnt, zero_cnt);

  // precompute reset values if workspace is big enough
  const float* sres = nullptr;
  size_t need = (size_t)(T - 1) * (size_t)N * sizeof(float);
  if (ws_size >= need) {
    snn_pre<<<dim3(T - 1), dim3(1024), 0, stream>>>(seed, (float*)d_ws);
    sres = (const float*)d_ws;
  }

  snn_sim<<<dim3(1), dim3(1024), 0, stream>>>(ts, v0, i0, ic, w, mu, seed, sres,
                                              (float*)d_out, T, MS);
}